// Round 1
// baseline (225.462 us; speedup 1.0000x reference)
//
#include <hip/hip_runtime.h>
#include <math.h>

// out[b, l, d] = x[b, l, d] + pe[l, d]
// pe[l, 0:128]   : interleaved sin/cos of row * freq_m   (m = 0..63)
// pe[l, 128:256] : interleaved sin/cos of col * freq_m
// freq_m = exp(-m * ln(10000)/64)
// l = row * w + col,  d_model = 256 (D_MODEL constant in the reference)

__global__ __launch_bounds__(256) void pe_add_kernel(
    const float* __restrict__ x,
    const int* __restrict__ hp,
    const int* __restrict__ wp,
    float* __restrict__ out,
    unsigned int n4)   // total number of float4 elements
{
    unsigned int idx = blockIdx.x * blockDim.x + threadIdx.x;
    if (idx >= n4) return;

    const unsigned int ww = (unsigned int)(*wp);
    const unsigned int hh = (unsigned int)(*hp);
    const unsigned int L  = hh * ww;

    unsigned int j = idx & 63u;   // which float4 within the 256-wide d dim
    unsigned int t = idx >> 6;    // b * L + l
    unsigned int l = t % L;
    unsigned int row = l / ww;
    unsigned int col = l - row * ww;

    unsigned int d0 = j << 2;           // starting channel (0..252, step 4)
    unsigned int dd = d0 & 127u;        // offset within the row/col half
    float pos = (float)((d0 < 128u) ? row : col);

    unsigned int m0 = dd >> 1;          // frequency index of first pair
    const float cstep = 0.14391156831212787f;  // ln(10000)/64
    float f0 = __expf(-(float)m0 * cstep);
    float f1 = __expf(-(float)(m0 + 1u) * cstep);
    float a0 = pos * f0;
    float a1 = pos * f1;

    float s0, c0, s1, c1;
    __sincosf(a0, &s0, &c0);
    __sincosf(a1, &s1, &c1);

    float4 xv = reinterpret_cast<const float4*>(x)[idx];
    float4 ov;
    ov.x = xv.x + s0;
    ov.y = xv.y + c0;
    ov.z = xv.z + s1;
    ov.w = xv.w + c1;
    reinterpret_cast<float4*>(out)[idx] = ov;
}

extern "C" void kernel_launch(void* const* d_in, const int* in_sizes, int n_in,
                              void* d_out, int out_size, void* d_ws, size_t ws_size,
                              hipStream_t stream) {
    const float* x = (const float*)d_in[0];
    const int* hp  = (const int*)d_in[1];
    const int* wp  = (const int*)d_in[2];
    float* out     = (float*)d_out;

    unsigned int n4 = (unsigned int)(out_size / 4);
    unsigned int blocks = (n4 + 255u) / 256u;
    pe_add_kernel<<<blocks, 256, 0, stream>>>(x, hp, wp, out, n4);
}